// Round 19
// baseline (184.145 us; speedup 1.0000x reference)
//
#include <hip/hip_runtime.h>

#define Cc 64
#define Dd 128
#define Nn 32
#define Kk 4
#define Rr 4
#define Bb 2
#define Hh 48
#define Ww 48
#define Ll 2304
#define EPSf 1e-5f
#define LCc 144   // scan chunk length = L/16

#if __has_builtin(__builtin_amdgcn_exp2f)
#define EXP2F __builtin_amdgcn_exp2f
#else
#define EXP2F exp2f
#endif

__device__ __forceinline__ float wsum64(float v) {
  v += __shfl_xor(v, 32);
  v += __shfl_xor(v, 16);
  v += __shfl_xor(v, 8);
  v += __shfl_xor(v, 4);
  v += __shfl_xor(v, 2);
  v += __shfl_xor(v, 1);
  return v;
}

// max over the 32 lanes of a half-wave (masks stay within the half)
__device__ __forceinline__ float hmax32(float v) {
  v = fmaxf(v, __shfl_xor(v, 1));
  v = fmaxf(v, __shfl_xor(v, 2));
  v = fmaxf(v, __shfl_xor(v, 4));
  v = fmaxf(v, __shfl_xor(v, 8));
  v = fmaxf(v, __shfl_xor(v, 16));
  return v;
}

// scan index j of direction k -> pixel index (block-uniform k; scalar branches)
__device__ __forceinline__ int pixbase(int j, int k) {
  if (k == 0) return j;
  if (k == 2) return Ll - 1 - j;
  if (k == 1) return (j % Hh) * Ww + (j / Hh);
  const int jr = Ll - 1 - j;
  return (jr % Hh) * Ww + (jr / Hh);
}

// ---------------- K1: pre-LN (over C) + in_proj (C -> 2D), split x/z ----------------
// r6-measured version (256 thr x 288 blocks, 4 px/wave W-amortization).
// xin PIXEL-MAJOR (b,l,d): written exactly like zb (coalesced 256B/instr).
__global__ __launch_bounds__(256) void k1_ln_inproj(
    const float* __restrict__ x, const float* __restrict__ g,
    const float* __restrict__ bta, const float* __restrict__ Wp,
    float* __restrict__ xin, float* __restrict__ zb)
{
  __shared__ float xS[16][65];
  __shared__ float xnS[16][64];
  const int tid = threadIdx.x;
  const int wv = tid >> 6, lane = tid & 63;
  const int pbase = blockIdx.x * 16;       // 4608 pixels total, no b-straddle
  const int b = pbase / Ll;
  const int lbase = pbase % Ll;
  {  // coalesced staging: thread -> (c, 4 consecutive l)
    const int c = tid >> 2, li0 = (tid & 3) * 4;
    const float4 v4 = *(const float4*)&x[(b * Cc + c) * Ll + lbase + li0];
    xS[li0 + 0][c] = v4.x;
    xS[li0 + 1][c] = v4.y;
    xS[li0 + 2][c] = v4.z;
    xS[li0 + 3][c] = v4.w;
  }
  __syncthreads();
  const float gv = g[lane], bv = bta[lane];
  for (int pi = 0; pi < 4; ++pi) {
    const int p = wv * 4 + pi;
    const float v = xS[p][lane];
    const float mu = wsum64(v) * (1.0f / 64.0f);
    const float dv = v - mu;
    const float var = wsum64(dv * dv) * (1.0f / 64.0f);
    const float rs = rsqrtf(var + EPSf);
    xnS[p][lane] = dv * rs * gv + bv;
  }
  __syncthreads();
  float acc[4][4];
  #pragma unroll
  for (int pi = 0; pi < 4; ++pi)
    #pragma unroll
    for (int m = 0; m < 4; ++m) acc[pi][m] = 0.f;
  const float4* W4 = (const float4*)Wp;
  #pragma unroll 4
  for (int c4 = 0; c4 < 16; ++c4) {
    float4 xn4[4];
    #pragma unroll
    for (int pi = 0; pi < 4; ++pi)
      xn4[pi] = ((const float4*)xnS[wv * 4 + pi])[c4];
    #pragma unroll
    for (int m = 0; m < 4; ++m) {
      const float4 w4 = W4[(lane + 64 * m) * 16 + c4];
      #pragma unroll
      for (int pi = 0; pi < 4; ++pi)
        acc[pi][m] += xn4[pi].x * w4.x + xn4[pi].y * w4.y +
                      xn4[pi].z * w4.z + xn4[pi].w * w4.w;
    }
  }
  #pragma unroll
  for (int pi = 0; pi < 4; ++pi) {
    const int l = lbase + wv * 4 + pi;
    const size_t base = (size_t)(b * Ll + l) * Dd;
    xin[base + lane]      = acc[pi][0];
    xin[base + lane + 64] = acc[pi][1];
    zb[base + lane]       = acc[pi][2];
    zb[base + lane + 64]  = acc[pi][3];
  }
}

// ---------------- K3: conv3x3+SiLU (fused) + projections -> xc, {delta,delta*u}, B, C ----------------
// dd2 pixel-major writes (verified r10). xin staging via float4 with xinS [col][d]
// (r11): 4x fewer staging instructions; conv reads conflict-free.
__global__ __launch_bounds__(512) void k3_proj(
    const float* __restrict__ xin, const float* __restrict__ cw,
    const float* __restrict__ cb, const float* __restrict__ xpw,
    const float* __restrict__ dtw, const float* __restrict__ dtb,
    float* __restrict__ xc, float2* __restrict__ dd2,
    float* __restrict__ Bm, float* __restrict__ Cm)
{
  __shared__ float xinS[30][128];   // [halo column][d]; lanes along d -> conflict-free
  __shared__ float xvS[8][132];
  __shared__ float dtsS[8][16];
  const int t = threadIdx.x;
  const int pb = blockIdx.x * 8;
  const int b = pb / Ll;
  const int lb = pb % Ll;
  const int h0 = lb / Ww, w0 = lb % Ww;
  // stage 3 rows x 10 cols x 128 d of xin (pixel-major): 960 float4, guarded per column
  for (int i = t; i < 960; i += 512) {
    const int j = i >> 5, d4 = i & 31;
    const int r = j / 10, c = j % 10;
    const int hh = h0 + r - 1, ww = w0 + c - 1;
    float4 v = make_float4(0.f, 0.f, 0.f, 0.f);
    if (hh >= 0 && hh < Hh && ww >= 0 && ww < Ww)
      v = *(const float4*)&xin[((size_t)(b * Ll) + hh * Ww + ww) * Dd + d4 * 4];
    *(float4*)&xinS[j][d4 * 4] = v;
  }
  __syncthreads();
  // depthwise conv + bias + SiLU -> xvS (pixel-major for the GEMM below)
  for (int i = t; i < 1024; i += 512) {
    const int pi = i >> 7, d = i & 127;
    float acc = cb[d];
    #pragma unroll
    for (int r = 0; r < 3; ++r)
      #pragma unroll
      for (int c = 0; c < 3; ++c)
        acc += xinS[r * 10 + pi + c][d] * cw[d * 9 + r * 3 + c];
    const float sig = 1.0f / (1.0f + __expf(-acc));
    xvS[pi][d] = acc * sig;
  }
  __syncthreads();
  if (t < 272) {   // projection GEMM: 4 k x 68 c rows, 8 px each
    const int k = t / 68, c = t % 68;
    const size_t bkL = (size_t)(b * Kk + k) * Ll;
    float acc[8];
    #pragma unroll
    for (int pi = 0; pi < 8; ++pi) acc[pi] = 0.f;
    const float4* w4p = (const float4*)(xpw + (k * 68 + c) * 128);
    for (int d4 = 0; d4 < 32; ++d4) {
      const float4 w4 = w4p[d4];
      #pragma unroll
      for (int pi = 0; pi < 8; ++pi) {
        const float4 x4 = ((const float4*)xvS[pi])[d4];
        acc[pi] += x4.x * w4.x + x4.y * w4.y + x4.z * w4.z + x4.w * w4.w;
      }
    }
    #pragma unroll
    for (int pi = 0; pi < 8; ++pi) {
      const int l0 = lb + pi;
      const int h = l0 / Ww, w = l0 % Ww;
      int lk;
      if      (k == 0) lk = l0;
      else if (k == 1) lk = w * Hh + h;
      else if (k == 2) lk = Ll - 1 - l0;
      else             lk = Ll - 1 - (w * Hh + h);
      if (c < Rr)            dtsS[pi][k * 4 + c] = acc[pi];
      else if (c < Rr + Nn)  Bm[(bkL + lk) * Nn + (c - Rr)] = acc[pi];
      else                   Cm[(bkL + lk) * Nn + (c - Rr - Nn)] = acc[pi];
    }
  } else {   // idle-during-proj threads handle the xc write (pixel-major, coalesced)
    for (int i = t - 272; i < 1024; i += 240) {
      const int pi = i >> 7, d = i & 127;
      xc[((size_t)(b * Ll) + lb + pi) * Dd + d] = xvS[pi][d];
    }
  }
  __syncthreads();
  {  // delta + softplus + pack {delta, delta*u}; PIXEL-major write for all k
    const int k = t >> 7, dd = t & 127;
    const float4 dw = *(const float4*)&dtw[(k * Dd + dd) * 4];
    const float biasv = dtb[k * Dd + dd];
    float2* drow = dd2 + ((size_t)((b * Kk + k) * Dd) + dd) * Ll;
    float2 buf[8];
    #pragma unroll
    for (int pi = 0; pi < 8; ++pi) {
      const float a = biasv
          + dtsS[pi][k * 4 + 0] * dw.x + dtsS[pi][k * 4 + 1] * dw.y
          + dtsS[pi][k * 4 + 2] * dw.z + dtsS[pi][k * 4 + 3] * dw.w;
      const float sp = (a > 20.f) ? a : log1pf(__expf(a));
      buf[pi] = make_float2(sp, sp * xvS[pi][dd]);
    }
    float4* f4 = (float4*)(drow + lb);
    #pragma unroll
    for (int j = 0; j < 4; ++j)
      f4[j] = make_float4(buf[2 * j].x, buf[2 * j].y, buf[2 * j + 1].x, buf[2 * j + 1].y);
  }
}

// ---------------- K4: DUAL-CHAIN scan + TILED truncated carry correction ----------------
// r17/r18 structure (measured 45.1us): each block processes a d-PAIR (d0, d0+1) of
// the same (b,k); two independent recurrence chains per thread fill the serial
// exp2->fma dependency bubbles; B/C (d-independent) loads shared.
// ONLY change vs r18: correction threshold eps 1e-4 -> 1e-3 (factor 3.2e5 -> 3.2e4).
// Rigorous additive error bound <= 1e-3, 7.8x under the harness threshold; r18's
// eps=1e-4 left absmax bit-identical, so budget is available. Shortens Pstop by
// another ~2.3 delta-units (~0.5-1 correction tile per chunk).
// block index = (dpair<<3)|(b*4+k): %8 XCD round-robin.
__global__ __launch_bounds__(512) void k4_scan(
    const float2* __restrict__ dd2, const float* __restrict__ Bm,
    const float* __restrict__ Cm, const float* __restrict__ Alogs,
    float* __restrict__ ys)
{
  __shared__ float2 ddS[2][Ll];     // 36KB: the d-pair's {delta, delta*u} rows
  __shared__ float hcS[2][16][32];  // hend (pass 1) THEN carry (aliased combine)
  __shared__ float sumDS[2][16];
  __shared__ float cmaxS[16];
  __shared__ float pSA[16][8][36];
  __shared__ float pSB[16][8][36];
  const int tid = threadIdx.x;
  const int s = tid >> 5, n = tid & 31;
  const int blk = blockIdx.x;
  const int bk = blk & 7;          // (b,k) -> XCD
  const int dp = blk >> 3;         // d-pair index 0..63
  const int d0 = dp * 2;
  const int b = bk >> 2, k = bk & 3;
  const float AnE0 = -__expf(Alogs[(k * Dd + d0) * Nn + n]) * 1.44269504f;
  const float AnE1 = -__expf(Alogs[(k * Dd + d0 + 1) * Nn + n]) * 1.44269504f;
  const size_t bkL = (size_t)(b * Kk + k) * Ll;
  const float2* dP0 = dd2 + ((size_t)((b * Kk + k) * Dd) + d0) * Ll;  // d0 row; d1 row adjacent
  const float* bP = Bm + bkL * Nn + n;
  const float* cP = Cm + bkL * Nn + n;
  const int lbeg = s * LCc;
  float* yD0 = ys + ((size_t)((b * Kk + k) * Dd) + d0) * Ll;  // pixel-space rows
  float* yD1 = yD0 + Ll;
  const int pstr = (k == 0) ? 1 : (k == 1) ? Ww : (k == 2) ? -1 : -Ww;
  const int rrow = n & 7, qtr = n >> 3;

  {  // stage both dd2 rows: 2304 float4, coalesced pixel-order copy (rows adjacent)
    const float4* src = (const float4*)dP0;
    float4* dst = (float4*)ddS;
    #pragma unroll
    for (int i = 0; i < 5; ++i) {
      const int idx = tid + i * 512;
      if (idx < Ll) dst[idx] = src[idx];   // Ll float4s = 2 rows x Ll float2
    }
  }
  __syncthreads();

  // ---- pass 1: dual local scans (carry=0), y_local out, hend + sumD + max|c| ----
  float h0 = 0.f, h1 = 0.f, sD0 = 0.f, sD1 = 0.f, cmx = 0.f;
  {
    const float* bl = bP + (size_t)lbeg * Nn;
    const float* cl = cP + (size_t)lbeg * Nn;
    float b0 = bl[0], b1 = bl[Nn], b2 = bl[2 * Nn], b3 = bl[3 * Nn];
    float c0 = cl[0], c1 = cl[Nn], c2 = cl[2 * Nn], c3 = cl[3 * Nn];
    int pb = pixbase(lbeg, k);
    float2 qa0 = ddS[0][pb], qa1 = ddS[0][pb + pstr],
           qa2 = ddS[0][pb + 2 * pstr], qa3 = ddS[0][pb + 3 * pstr];
    float2 qb0 = ddS[1][pb], qb1 = ddS[1][pb + pstr],
           qb2 = ddS[1][pb + 2 * pstr], qb3 = ddS[1][pb + 3 * pstr];
    for (int t8 = 0; t8 < LCc / 8; ++t8) {
      const int j0n = lbeg + t8 * 8 + 8;
      const int pbn = pixbase(j0n <= Ll - 8 ? j0n : Ll - 8, k);  // next-tile base (clamped)
      #pragma unroll
      for (int half = 0; half < 2; ++half) {
        bl += 4 * Nn; cl += 4 * Nn;   // shared B/C prefetch (overread guarded by ws layout)
        const int gb = (half == 0) ? pb + 4 * pstr : pbn;
        const float2 na0 = ddS[0][gb], na1 = ddS[0][gb + pstr],
                     na2 = ddS[0][gb + 2 * pstr], na3 = ddS[0][gb + 3 * pstr];
        const float2 nb0 = ddS[1][gb], nb1 = ddS[1][gb + pstr],
                     nb2 = ddS[1][gb + 2 * pstr], nb3 = ddS[1][gb + 3 * pstr];
        const float b0n = bl[0], b1n = bl[Nn], b2n = bl[2 * Nn], b3n = bl[3 * Nn];
        const float c0n = cl[0], c1n = cl[Nn], c2n = cl[2 * Nn], c3n = cl[3 * Nn];
        h0 = EXP2F(qa0.x * AnE0) * h0 + qa0.y * b0; pSA[s][half * 4 + 0][n] = h0 * c0;
        h1 = EXP2F(qb0.x * AnE1) * h1 + qb0.y * b0; pSB[s][half * 4 + 0][n] = h1 * c0;
        h0 = EXP2F(qa1.x * AnE0) * h0 + qa1.y * b1; pSA[s][half * 4 + 1][n] = h0 * c1;
        h1 = EXP2F(qb1.x * AnE1) * h1 + qb1.y * b1; pSB[s][half * 4 + 1][n] = h1 * c1;
        h0 = EXP2F(qa2.x * AnE0) * h0 + qa2.y * b2; pSA[s][half * 4 + 2][n] = h0 * c2;
        h1 = EXP2F(qb2.x * AnE1) * h1 + qb2.y * b2; pSB[s][half * 4 + 2][n] = h1 * c2;
        h0 = EXP2F(qa3.x * AnE0) * h0 + qa3.y * b3; pSA[s][half * 4 + 3][n] = h0 * c3;
        h1 = EXP2F(qb3.x * AnE1) * h1 + qb3.y * b3; pSB[s][half * 4 + 3][n] = h1 * c3;
        sD0 += (qa0.x + qa1.x) + (qa2.x + qa3.x);
        sD1 += (qb0.x + qb1.x) + (qb2.x + qb3.x);
        cmx = fmaxf(cmx, fmaxf(fmaxf(fabsf(c0), fabsf(c1)),
                               fmaxf(fabsf(c2), fabsf(c3))));
        qa0 = na0; qa1 = na1; qa2 = na2; qa3 = na3;
        qb0 = nb0; qb1 = nb1; qb2 = nb2; qb3 = nb3;
        b0 = b0n; b1 = b1n; b2 = b2n; b3 = b3n;
        c0 = c0n; c1 = c1n; c2 = c2n; c3 = c3n;
      }
      {  // reduce both 8-step tiles (independent -> more ILP)
        const float4 a4 = *(const float4*)&pSA[s][rrow][qtr * 8];
        const float4 d4v = *(const float4*)&pSA[s][rrow][qtr * 8 + 4];
        float sumA = ((a4.x + a4.y) + (a4.z + a4.w)) + ((d4v.x + d4v.y) + (d4v.z + d4v.w));
        const float4 e4 = *(const float4*)&pSB[s][rrow][qtr * 8];
        const float4 f4 = *(const float4*)&pSB[s][rrow][qtr * 8 + 4];
        float sumB = ((e4.x + e4.y) + (e4.z + e4.w)) + ((f4.x + f4.y) + (f4.z + f4.w));
        sumA += __shfl_xor(sumA, 8);
        sumB += __shfl_xor(sumB, 8);
        sumA += __shfl_xor(sumA, 16);
        sumB += __shfl_xor(sumB, 16);
        if (n < 8) {
          yD0[pb + n * pstr] = sumA;
          yD1[pb + n * pstr] = sumB;
        }
      }
      pb = pbn;
    }
  }
  hcS[0][s][n] = h0;
  hcS[1][s][n] = h1;
  const float cmxAll = hmax32(cmx);
  if (n == 0) { sumDS[0][s] = sD0; sumDS[1][s] = sD1; cmaxS[s] = cmxAll; }
  __syncthreads();
  // ---- exact serial carry combine, both chains in parallel (tid<64); hcS: hend->carry ----
  if (tid < 64) {
    const int ch = tid >> 5, ln = tid & 31;   // thread tid<64 has n==ln -> correct AnE
    const float AnE = (ch == 0) ? AnE0 : AnE1;
    float carry = 0.f;
    #pragma unroll
    for (int s2 = 0; s2 < 16; ++s2) {
      const float hend = hcS[ch][s2][ln];   // read hend BEFORE overwriting the slot
      hcS[ch][s2][ln] = carry;              // entering carry for chunk s2
      carry = EXP2F(AnE * sumDS[ch][s2]) * carry + hend;
    }
  }
  __syncthreads();
  // ---- truncated carry correction, dual-chain, tiled like pass 1 ----
  const float carryA = hcS[0][s][n], carryB = hcS[1][s][n];
  const float mcA = hmax32(fabsf(carryA));
  const float mcB = hmax32(fabsf(carryB));
  const float AmaxE0 = hmax32(AnE0);             // all < 0; max = slowest decay
  const float AmaxE1 = hmax32(AnE1);
  // smallest P with 32*mc*cmax*2^(AmaxE*P) <= 1e-3  (log2f(0) = -inf => skip)
  const float Pstop0 = log2f(mcA * cmaxS[s] * 3.2e4f) / (-AmaxE0);
  const float Pstop1 = log2f(mcB * cmaxS[s] * 3.2e4f) / (-AmaxE1);
  {
    float hA = carryA, hB = carryB, P0 = 0.f, P1 = 0.f;
    const float* cl = cP + (size_t)lbeg * Nn;
    for (int t8 = 0; t8 < LCc / 8; ++t8) {
      if (!(P0 < Pstop0) && !(P1 < Pstop1)) break;   // uniform per half-wave
      const int pb = pixbase(lbeg + t8 * 8, k);
      #pragma unroll
      for (int half = 0; half < 2; ++half) {
        const int gb = pb + half * 4 * pstr;
        const float2 u0 = ddS[0][gb], u1 = ddS[0][gb + pstr],
                     u2 = ddS[0][gb + 2 * pstr], u3 = ddS[0][gb + 3 * pstr];
        const float2 v0 = ddS[1][gb], v1 = ddS[1][gb + pstr],
                     v2 = ddS[1][gb + 2 * pstr], v3 = ddS[1][gb + 3 * pstr];
        hA *= EXP2F(u0.x * AnE0); pSA[s][half * 4 + 0][n] = hA * cl[0];
        hB *= EXP2F(v0.x * AnE1); pSB[s][half * 4 + 0][n] = hB * cl[0];
        hA *= EXP2F(u1.x * AnE0); pSA[s][half * 4 + 1][n] = hA * cl[Nn];
        hB *= EXP2F(v1.x * AnE1); pSB[s][half * 4 + 1][n] = hB * cl[Nn];
        hA *= EXP2F(u2.x * AnE0); pSA[s][half * 4 + 2][n] = hA * cl[2 * Nn];
        hB *= EXP2F(v2.x * AnE1); pSB[s][half * 4 + 2][n] = hB * cl[2 * Nn];
        hA *= EXP2F(u3.x * AnE0); pSA[s][half * 4 + 3][n] = hA * cl[3 * Nn];
        hB *= EXP2F(v3.x * AnE1); pSB[s][half * 4 + 3][n] = hB * cl[3 * Nn];
        P0 += (u0.x + u1.x) + (u2.x + u3.x);
        P1 += (v0.x + v1.x) + (v2.x + v3.x);
        cl += 4 * Nn;
      }
      const float4 a4 = *(const float4*)&pSA[s][rrow][qtr * 8];
      const float4 d4v = *(const float4*)&pSA[s][rrow][qtr * 8 + 4];
      float sumA = ((a4.x + a4.y) + (a4.z + a4.w)) + ((d4v.x + d4v.y) + (d4v.z + d4v.w));
      const float4 e4 = *(const float4*)&pSB[s][rrow][qtr * 8];
      const float4 f4 = *(const float4*)&pSB[s][rrow][qtr * 8 + 4];
      float sumB = ((e4.x + e4.y) + (e4.z + e4.w)) + ((f4.x + f4.y) + (f4.z + f4.w));
      sumA += __shfl_xor(sumA, 8);
      sumB += __shfl_xor(sumB, 8);
      sumA += __shfl_xor(sumA, 16);
      sumB += __shfl_xor(sumB, 16);
      if (n < 8) {
        yD0[pb + n * pstr] += sumA;   // below-threshold adds are harmless (more exact)
        yD1[pb + n * pstr] += sumB;
      }
    }
  }
}

// ---------------- K5: merge + Ds-term + out-LN + SiLU(z)* + out_proj + residual ----------------
// r13 version: 4 direction planes summed in registers during staging (ysS single
// plane, 8.4KB); block LDS ~29KB -> 5 blocks/CU.
__global__ __launch_bounds__(256) void k5_merge(
    const float* __restrict__ ys, const float* __restrict__ zb,
    const float* __restrict__ og, const float* __restrict__ ob,
    const float* __restrict__ Wo, const float* __restrict__ resid,
    const float* __restrict__ xc, const float* __restrict__ DsP,
    float* __restrict__ out)
{
  __shared__ float ysS[16][132];   // 132: break the d-stride bank alias
  __shared__ float xcS[16][128];
  __shared__ float tS[16][128];
  __shared__ float oS[64][17];
  const int tid = threadIdx.x;
  const int wv = tid >> 6, lane = tid & 63;
  const int pbase = blockIdx.x * 16;   // 16 consecutive l (16 | 48: no row straddle)
  const int b = pbase / Ll;
  const int lbase = pbase % Ll;
  {  // ys staging with 4-dir register sum: thread -> (d = tid>>2 (+64), float4 at l)
    const int li0 = (tid & 3) * 4, dh = tid >> 2;
    #pragma unroll
    for (int it = 0; it < 2; ++it) {
      const int d = dh + 64 * it;
      float4 acc = make_float4(0.f, 0.f, 0.f, 0.f);
      #pragma unroll
      for (int k = 0; k < 4; ++k) {
        const float4 v = *(const float4*)&ys[((size_t)(b * Kk + k) * Dd + d) * Ll + lbase + li0];
        acc.x += v.x; acc.y += v.y; acc.z += v.z; acc.w += v.w;
      }
      ysS[li0 + 0][d] = acc.x; ysS[li0 + 1][d] = acc.y;
      ysS[li0 + 2][d] = acc.z; ysS[li0 + 3][d] = acc.w;
    }
  }
  {  // xc (pixel-major): lanes along d, fully coalesced
    const int p = tid >> 4, q = tid & 15;
    const float4* src = (const float4*)&xc[((size_t)(b * Ll) + lbase + p) * Dd];
    ((float4*)xcS[p])[q]      = src[q];
    ((float4*)xcS[p])[q + 16] = src[q + 16];
  }
  float sDs[2];
  #pragma unroll
  for (int m = 0; m < 2; ++m) {
    const int dch = lane + 64 * m;
    sDs[m] = DsP[dch] + DsP[Dd + dch] + DsP[2 * Dd + dch] + DsP[3 * Dd + dch];
  }
  __syncthreads();
  for (int pi = 0; pi < 4; ++pi) {
    const int p = wv * 4 + pi;
    const int l0 = lbase + p;
    float tv[2];
    #pragma unroll
    for (int m = 0; m < 2; ++m) {
      const int dch = lane + 64 * m;
      tv[m] = ysS[p][dch] + sDs[m] * xcS[p][dch];
    }
    const float mu = wsum64(tv[0] + tv[1]) * (1.0f / 128.0f);
    const float q = wsum64((tv[0] - mu) * (tv[0] - mu) +
                           (tv[1] - mu) * (tv[1] - mu)) * (1.0f / 128.0f);
    const float rs = rsqrtf(q + EPSf);
    #pragma unroll
    for (int m = 0; m < 2; ++m) {
      const int dch = lane + 64 * m;
      const float zz = zb[(size_t)(b * Ll + l0) * Dd + dch];
      const float sig = 1.0f / (1.0f + __expf(-zz));
      tS[p][dch] = ((tv[m] - mu) * rs * og[dch] + ob[dch]) * (zz * sig);
    }
  }
  __syncthreads();
  float acc[4] = {0.f, 0.f, 0.f, 0.f};
  const float4* W4 = (const float4*)Wo;     // out_proj_w (64,128)
  for (int d4 = 0; d4 < 32; ++d4) {
    const float4 w4 = W4[lane * 32 + d4];
    #pragma unroll
    for (int pi = 0; pi < 4; ++pi) {
      const float4 t4 = ((const float4*)tS[wv * 4 + pi])[d4];
      acc[pi] += t4.x * w4.x + t4.y * w4.y + t4.z * w4.z + t4.w * w4.w;
    }
  }
  #pragma unroll
  for (int pi = 0; pi < 4; ++pi) oS[lane][wv * 4 + pi] = acc[pi];
  __syncthreads();
  const int c = tid >> 2, off = (tid & 3) * 4;
  const size_t obase = (size_t)(b * Cc + c) * Ll + lbase + off;
  const float4 r4 = *(const float4*)(resid + obase);
  float4 o4;
  o4.x = oS[c][off + 0] + r4.x;
  o4.y = oS[c][off + 1] + r4.y;
  o4.z = oS[c][off + 2] + r4.z;
  o4.w = oS[c][off + 3] + r4.w;
  *(float4*)(out + obase) = o4;
}

extern "C" void kernel_launch(void* const* d_in, const int* in_sizes, int n_in,
                              void* d_out, int out_size, void* d_ws, size_t ws_size,
                              hipStream_t stream)
{
  (void)in_sizes; (void)n_in; (void)out_size; (void)ws_size;
  const float* fufea1     = (const float*)d_in[0];
  const float* ln_g       = (const float*)d_in[1];
  const float* ln_b       = (const float*)d_in[2];
  const float* in_proj_w  = (const float*)d_in[3];
  const float* conv_w     = (const float*)d_in[4];
  const float* conv_b     = (const float*)d_in[5];
  const float* x_proj_w   = (const float*)d_in[6];
  const float* dt_w       = (const float*)d_in[7];
  const float* dt_b       = (const float*)d_in[8];
  const float* A_logs     = (const float*)d_in[9];
  const float* Ds         = (const float*)d_in[10];
  const float* out_ln_g   = (const float*)d_in[11];
  const float* out_ln_b   = (const float*)d_in[12];
  const float* out_proj_w = (const float*)d_in[13];

  float* ws = (float*)d_ws;
  // k4's 1-deep B/C prefetch overreads a few hundred bytes past Bm/Cm row ends
  // -> keep a live buffer after each (Bm -> Cm -> zb). dd2 is read via an exact
  // in-bounds LDS copy (no overread).
  float2* dd2 = (float2*)ws;        // (B,K,D,L) float2, PIXEL-major l  4718592 floats
  float* Bm   = ws + 4718592;       // (B,K,L,N) scan-major             589824
  float* Cm   = ws + 5308416;       // (B,K,L,N) scan-major             589824
  float* zb   = ws + 5898240;       // (B,L,D)                          589824
  float* xc   = ws + 6488064;       // (B,L,D) pixel-major              589824
  float* ysb  = ws + 7077888;       // (B,K,D,L) PIXEL-space l         2359296
  float* xin  = ws + 7077888;       // (B,L,D) pixel-major — overlaps ysb (dead before k4)
  // total: 9437184 floats = 37.75 MB

  k1_ln_inproj<<<288, 256, 0, stream>>>(fufea1, ln_g, ln_b, in_proj_w, xin, zb);
  k3_proj<<<576, 512, 0, stream>>>(xin, conv_w, conv_b, x_proj_w, dt_w, dt_b,
                                   xc, dd2, Bm, Cm);
  k4_scan<<<512, 512, 0, stream>>>(dd2, Bm, Cm, A_logs, ysb);
  k5_merge<<<288, 256, 0, stream>>>(ysb, zb, out_ln_g, out_ln_b, out_proj_w, fufea1,
                                    xc, Ds, (float*)d_out);
}

// Round 20
// 183.398 us; speedup vs baseline: 1.0041x; 1.0041x over previous
//
#include <hip/hip_runtime.h>

#define Cc 64
#define Dd 128
#define Nn 32
#define Kk 4
#define Rr 4
#define Bb 2
#define Hh 48
#define Ww 48
#define Ll 2304
#define EPSf 1e-5f
#define LCc 144   // scan chunk length = L/16

#if __has_builtin(__builtin_amdgcn_exp2f)
#define EXP2F __builtin_amdgcn_exp2f
#else
#define EXP2F exp2f
#endif

__device__ __forceinline__ float wsum64(float v) {
  v += __shfl_xor(v, 32);
  v += __shfl_xor(v, 16);
  v += __shfl_xor(v, 8);
  v += __shfl_xor(v, 4);
  v += __shfl_xor(v, 2);
  v += __shfl_xor(v, 1);
  return v;
}

// max over the 32 lanes of a half-wave (masks stay within the half)
__device__ __forceinline__ float hmax32(float v) {
  v = fmaxf(v, __shfl_xor(v, 1));
  v = fmaxf(v, __shfl_xor(v, 2));
  v = fmaxf(v, __shfl_xor(v, 4));
  v = fmaxf(v, __shfl_xor(v, 8));
  v = fmaxf(v, __shfl_xor(v, 16));
  return v;
}

// scan index j of direction k -> pixel index (block-uniform k; scalar branches)
__device__ __forceinline__ int pixbase(int j, int k) {
  if (k == 0) return j;
  if (k == 2) return Ll - 1 - j;
  if (k == 1) return (j % Hh) * Ww + (j / Hh);
  const int jr = Ll - 1 - j;
  return (jr % Hh) * Ww + (jr / Hh);
}

// ---------------- K1: pre-LN (over C) + in_proj (C -> 2D), split x/z ----------------
// r6-measured version (256 thr x 288 blocks, 4 px/wave W-amortization).
// xin PIXEL-MAJOR (b,l,d): written exactly like zb (coalesced 256B/instr).
__global__ __launch_bounds__(256) void k1_ln_inproj(
    const float* __restrict__ x, const float* __restrict__ g,
    const float* __restrict__ bta, const float* __restrict__ Wp,
    float* __restrict__ xin, float* __restrict__ zb)
{
  __shared__ float xS[16][65];
  __shared__ float xnS[16][64];
  const int tid = threadIdx.x;
  const int wv = tid >> 6, lane = tid & 63;
  const int pbase = blockIdx.x * 16;       // 4608 pixels total, no b-straddle
  const int b = pbase / Ll;
  const int lbase = pbase % Ll;
  {  // coalesced staging: thread -> (c, 4 consecutive l)
    const int c = tid >> 2, li0 = (tid & 3) * 4;
    const float4 v4 = *(const float4*)&x[(b * Cc + c) * Ll + lbase + li0];
    xS[li0 + 0][c] = v4.x;
    xS[li0 + 1][c] = v4.y;
    xS[li0 + 2][c] = v4.z;
    xS[li0 + 3][c] = v4.w;
  }
  __syncthreads();
  const float gv = g[lane], bv = bta[lane];
  for (int pi = 0; pi < 4; ++pi) {
    const int p = wv * 4 + pi;
    const float v = xS[p][lane];
    const float mu = wsum64(v) * (1.0f / 64.0f);
    const float dv = v - mu;
    const float var = wsum64(dv * dv) * (1.0f / 64.0f);
    const float rs = rsqrtf(var + EPSf);
    xnS[p][lane] = dv * rs * gv + bv;
  }
  __syncthreads();
  float acc[4][4];
  #pragma unroll
  for (int pi = 0; pi < 4; ++pi)
    #pragma unroll
    for (int m = 0; m < 4; ++m) acc[pi][m] = 0.f;
  const float4* W4 = (const float4*)Wp;
  #pragma unroll 4
  for (int c4 = 0; c4 < 16; ++c4) {
    float4 xn4[4];
    #pragma unroll
    for (int pi = 0; pi < 4; ++pi)
      xn4[pi] = ((const float4*)xnS[wv * 4 + pi])[c4];
    #pragma unroll
    for (int m = 0; m < 4; ++m) {
      const float4 w4 = W4[(lane + 64 * m) * 16 + c4];
      #pragma unroll
      for (int pi = 0; pi < 4; ++pi)
        acc[pi][m] += xn4[pi].x * w4.x + xn4[pi].y * w4.y +
                      xn4[pi].z * w4.z + xn4[pi].w * w4.w;
    }
  }
  #pragma unroll
  for (int pi = 0; pi < 4; ++pi) {
    const int l = lbase + wv * 4 + pi;
    const size_t base = (size_t)(b * Ll + l) * Dd;
    xin[base + lane]      = acc[pi][0];
    xin[base + lane + 64] = acc[pi][1];
    zb[base + lane]       = acc[pi][2];
    zb[base + lane + 64]  = acc[pi][3];
  }
}

// ---------------- K3: conv3x3+SiLU (fused) + projections -> xc, {delta,delta*u}, B, C ----------------
// dd2 pixel-major writes (verified r10). xin staging via float4 with xinS [col][d]
// (r11): 4x fewer staging instructions; conv reads conflict-free.
__global__ __launch_bounds__(512) void k3_proj(
    const float* __restrict__ xin, const float* __restrict__ cw,
    const float* __restrict__ cb, const float* __restrict__ xpw,
    const float* __restrict__ dtw, const float* __restrict__ dtb,
    float* __restrict__ xc, float2* __restrict__ dd2,
    float* __restrict__ Bm, float* __restrict__ Cm)
{
  __shared__ float xinS[30][128];   // [halo column][d]; lanes along d -> conflict-free
  __shared__ float xvS[8][132];
  __shared__ float dtsS[8][16];
  const int t = threadIdx.x;
  const int pb = blockIdx.x * 8;
  const int b = pb / Ll;
  const int lb = pb % Ll;
  const int h0 = lb / Ww, w0 = lb % Ww;
  // stage 3 rows x 10 cols x 128 d of xin (pixel-major): 960 float4, guarded per column
  for (int i = t; i < 960; i += 512) {
    const int j = i >> 5, d4 = i & 31;
    const int r = j / 10, c = j % 10;
    const int hh = h0 + r - 1, ww = w0 + c - 1;
    float4 v = make_float4(0.f, 0.f, 0.f, 0.f);
    if (hh >= 0 && hh < Hh && ww >= 0 && ww < Ww)
      v = *(const float4*)&xin[((size_t)(b * Ll) + hh * Ww + ww) * Dd + d4 * 4];
    *(float4*)&xinS[j][d4 * 4] = v;
  }
  __syncthreads();
  // depthwise conv + bias + SiLU -> xvS (pixel-major for the GEMM below)
  for (int i = t; i < 1024; i += 512) {
    const int pi = i >> 7, d = i & 127;
    float acc = cb[d];
    #pragma unroll
    for (int r = 0; r < 3; ++r)
      #pragma unroll
      for (int c = 0; c < 3; ++c)
        acc += xinS[r * 10 + pi + c][d] * cw[d * 9 + r * 3 + c];
    const float sig = 1.0f / (1.0f + __expf(-acc));
    xvS[pi][d] = acc * sig;
  }
  __syncthreads();
  if (t < 272) {   // projection GEMM: 4 k x 68 c rows, 8 px each
    const int k = t / 68, c = t % 68;
    const size_t bkL = (size_t)(b * Kk + k) * Ll;
    float acc[8];
    #pragma unroll
    for (int pi = 0; pi < 8; ++pi) acc[pi] = 0.f;
    const float4* w4p = (const float4*)(xpw + (k * 68 + c) * 128);
    for (int d4 = 0; d4 < 32; ++d4) {
      const float4 w4 = w4p[d4];
      #pragma unroll
      for (int pi = 0; pi < 8; ++pi) {
        const float4 x4 = ((const float4*)xvS[pi])[d4];
        acc[pi] += x4.x * w4.x + x4.y * w4.y + x4.z * w4.z + x4.w * w4.w;
      }
    }
    #pragma unroll
    for (int pi = 0; pi < 8; ++pi) {
      const int l0 = lb + pi;
      const int h = l0 / Ww, w = l0 % Ww;
      int lk;
      if      (k == 0) lk = l0;
      else if (k == 1) lk = w * Hh + h;
      else if (k == 2) lk = Ll - 1 - l0;
      else             lk = Ll - 1 - (w * Hh + h);
      if (c < Rr)            dtsS[pi][k * 4 + c] = acc[pi];
      else if (c < Rr + Nn)  Bm[(bkL + lk) * Nn + (c - Rr)] = acc[pi];
      else                   Cm[(bkL + lk) * Nn + (c - Rr - Nn)] = acc[pi];
    }
  } else {   // idle-during-proj threads handle the xc write (pixel-major, coalesced)
    for (int i = t - 272; i < 1024; i += 240) {
      const int pi = i >> 7, d = i & 127;
      xc[((size_t)(b * Ll) + lb + pi) * Dd + d] = xvS[pi][d];
    }
  }
  __syncthreads();
  {  // delta + softplus + pack {delta, delta*u}; PIXEL-major write for all k
    const int k = t >> 7, dd = t & 127;
    const float4 dw = *(const float4*)&dtw[(k * Dd + dd) * 4];
    const float biasv = dtb[k * Dd + dd];
    float2* drow = dd2 + ((size_t)((b * Kk + k) * Dd) + dd) * Ll;
    float2 buf[8];
    #pragma unroll
    for (int pi = 0; pi < 8; ++pi) {
      const float a = biasv
          + dtsS[pi][k * 4 + 0] * dw.x + dtsS[pi][k * 4 + 1] * dw.y
          + dtsS[pi][k * 4 + 2] * dw.z + dtsS[pi][k * 4 + 3] * dw.w;
      const float sp = (a > 20.f) ? a : log1pf(__expf(a));
      buf[pi] = make_float2(sp, sp * xvS[pi][dd]);
    }
    float4* f4 = (float4*)(drow + lb);
    #pragma unroll
    for (int j = 0; j < 4; ++j)
      f4[j] = make_float4(buf[2 * j].x, buf[2 * j].y, buf[2 * j + 1].x, buf[2 * j + 1].y);
  }
}

// ---------------- K4: DUAL-CHAIN scan + TILED truncated carry correction ----------------
// FINAL configuration (= r18, best measured 184.07us total / 45.1us k4):
// each block processes a d-PAIR (d0, d0+1) of the same (b,k); two independent
// recurrence chains per thread fill the serial exp2->fma dependency bubbles; B/C
// (d-independent) loads shared. Correction threshold eps = 1e-4 (r19 measured
// eps=1e-3 time-neutral -> keep the 10x tighter rigorous bound).
// block index = (dpair<<3)|(b*4+k): %8 XCD round-robin.
__global__ __launch_bounds__(512) void k4_scan(
    const float2* __restrict__ dd2, const float* __restrict__ Bm,
    const float* __restrict__ Cm, const float* __restrict__ Alogs,
    float* __restrict__ ys)
{
  __shared__ float2 ddS[2][Ll];     // 36KB: the d-pair's {delta, delta*u} rows
  __shared__ float hcS[2][16][32];  // hend (pass 1) THEN carry (aliased combine)
  __shared__ float sumDS[2][16];
  __shared__ float cmaxS[16];
  __shared__ float pSA[16][8][36];
  __shared__ float pSB[16][8][36];
  const int tid = threadIdx.x;
  const int s = tid >> 5, n = tid & 31;
  const int blk = blockIdx.x;
  const int bk = blk & 7;          // (b,k) -> XCD
  const int dp = blk >> 3;         // d-pair index 0..63
  const int d0 = dp * 2;
  const int b = bk >> 2, k = bk & 3;
  const float AnE0 = -__expf(Alogs[(k * Dd + d0) * Nn + n]) * 1.44269504f;
  const float AnE1 = -__expf(Alogs[(k * Dd + d0 + 1) * Nn + n]) * 1.44269504f;
  const size_t bkL = (size_t)(b * Kk + k) * Ll;
  const float2* dP0 = dd2 + ((size_t)((b * Kk + k) * Dd) + d0) * Ll;  // d0 row; d1 row adjacent
  const float* bP = Bm + bkL * Nn + n;
  const float* cP = Cm + bkL * Nn + n;
  const int lbeg = s * LCc;
  float* yD0 = ys + ((size_t)((b * Kk + k) * Dd) + d0) * Ll;  // pixel-space rows
  float* yD1 = yD0 + Ll;
  const int pstr = (k == 0) ? 1 : (k == 1) ? Ww : (k == 2) ? -1 : -Ww;
  const int rrow = n & 7, qtr = n >> 3;

  {  // stage both dd2 rows: 2304 float4, coalesced pixel-order copy (rows adjacent)
    const float4* src = (const float4*)dP0;
    float4* dst = (float4*)ddS;
    #pragma unroll
    for (int i = 0; i < 5; ++i) {
      const int idx = tid + i * 512;
      if (idx < Ll) dst[idx] = src[idx];   // Ll float4s = 2 rows x Ll float2
    }
  }
  __syncthreads();

  // ---- pass 1: dual local scans (carry=0), y_local out, hend + sumD + max|c| ----
  float h0 = 0.f, h1 = 0.f, sD0 = 0.f, sD1 = 0.f, cmx = 0.f;
  {
    const float* bl = bP + (size_t)lbeg * Nn;
    const float* cl = cP + (size_t)lbeg * Nn;
    float b0 = bl[0], b1 = bl[Nn], b2 = bl[2 * Nn], b3 = bl[3 * Nn];
    float c0 = cl[0], c1 = cl[Nn], c2 = cl[2 * Nn], c3 = cl[3 * Nn];
    int pb = pixbase(lbeg, k);
    float2 qa0 = ddS[0][pb], qa1 = ddS[0][pb + pstr],
           qa2 = ddS[0][pb + 2 * pstr], qa3 = ddS[0][pb + 3 * pstr];
    float2 qb0 = ddS[1][pb], qb1 = ddS[1][pb + pstr],
           qb2 = ddS[1][pb + 2 * pstr], qb3 = ddS[1][pb + 3 * pstr];
    for (int t8 = 0; t8 < LCc / 8; ++t8) {
      const int j0n = lbeg + t8 * 8 + 8;
      const int pbn = pixbase(j0n <= Ll - 8 ? j0n : Ll - 8, k);  // next-tile base (clamped)
      #pragma unroll
      for (int half = 0; half < 2; ++half) {
        bl += 4 * Nn; cl += 4 * Nn;   // shared B/C prefetch (overread guarded by ws layout)
        const int gb = (half == 0) ? pb + 4 * pstr : pbn;
        const float2 na0 = ddS[0][gb], na1 = ddS[0][gb + pstr],
                     na2 = ddS[0][gb + 2 * pstr], na3 = ddS[0][gb + 3 * pstr];
        const float2 nb0 = ddS[1][gb], nb1 = ddS[1][gb + pstr],
                     nb2 = ddS[1][gb + 2 * pstr], nb3 = ddS[1][gb + 3 * pstr];
        const float b0n = bl[0], b1n = bl[Nn], b2n = bl[2 * Nn], b3n = bl[3 * Nn];
        const float c0n = cl[0], c1n = cl[Nn], c2n = cl[2 * Nn], c3n = cl[3 * Nn];
        h0 = EXP2F(qa0.x * AnE0) * h0 + qa0.y * b0; pSA[s][half * 4 + 0][n] = h0 * c0;
        h1 = EXP2F(qb0.x * AnE1) * h1 + qb0.y * b0; pSB[s][half * 4 + 0][n] = h1 * c0;
        h0 = EXP2F(qa1.x * AnE0) * h0 + qa1.y * b1; pSA[s][half * 4 + 1][n] = h0 * c1;
        h1 = EXP2F(qb1.x * AnE1) * h1 + qb1.y * b1; pSB[s][half * 4 + 1][n] = h1 * c1;
        h0 = EXP2F(qa2.x * AnE0) * h0 + qa2.y * b2; pSA[s][half * 4 + 2][n] = h0 * c2;
        h1 = EXP2F(qb2.x * AnE1) * h1 + qb2.y * b2; pSB[s][half * 4 + 2][n] = h1 * c2;
        h0 = EXP2F(qa3.x * AnE0) * h0 + qa3.y * b3; pSA[s][half * 4 + 3][n] = h0 * c3;
        h1 = EXP2F(qb3.x * AnE1) * h1 + qb3.y * b3; pSB[s][half * 4 + 3][n] = h1 * c3;
        sD0 += (qa0.x + qa1.x) + (qa2.x + qa3.x);
        sD1 += (qb0.x + qb1.x) + (qb2.x + qb3.x);
        cmx = fmaxf(cmx, fmaxf(fmaxf(fabsf(c0), fabsf(c1)),
                               fmaxf(fabsf(c2), fabsf(c3))));
        qa0 = na0; qa1 = na1; qa2 = na2; qa3 = na3;
        qb0 = nb0; qb1 = nb1; qb2 = nb2; qb3 = nb3;
        b0 = b0n; b1 = b1n; b2 = b2n; b3 = b3n;
        c0 = c0n; c1 = c1n; c2 = c2n; c3 = c3n;
      }
      {  // reduce both 8-step tiles (independent -> more ILP)
        const float4 a4 = *(const float4*)&pSA[s][rrow][qtr * 8];
        const float4 d4v = *(const float4*)&pSA[s][rrow][qtr * 8 + 4];
        float sumA = ((a4.x + a4.y) + (a4.z + a4.w)) + ((d4v.x + d4v.y) + (d4v.z + d4v.w));
        const float4 e4 = *(const float4*)&pSB[s][rrow][qtr * 8];
        const float4 f4 = *(const float4*)&pSB[s][rrow][qtr * 8 + 4];
        float sumB = ((e4.x + e4.y) + (e4.z + e4.w)) + ((f4.x + f4.y) + (f4.z + f4.w));
        sumA += __shfl_xor(sumA, 8);
        sumB += __shfl_xor(sumB, 8);
        sumA += __shfl_xor(sumA, 16);
        sumB += __shfl_xor(sumB, 16);
        if (n < 8) {
          yD0[pb + n * pstr] = sumA;
          yD1[pb + n * pstr] = sumB;
        }
      }
      pb = pbn;
    }
  }
  hcS[0][s][n] = h0;
  hcS[1][s][n] = h1;
  const float cmxAll = hmax32(cmx);
  if (n == 0) { sumDS[0][s] = sD0; sumDS[1][s] = sD1; cmaxS[s] = cmxAll; }
  __syncthreads();
  // ---- exact serial carry combine, both chains in parallel (tid<64); hcS: hend->carry ----
  if (tid < 64) {
    const int ch = tid >> 5, ln = tid & 31;   // thread tid<64 has n==ln -> correct AnE
    const float AnE = (ch == 0) ? AnE0 : AnE1;
    float carry = 0.f;
    #pragma unroll
    for (int s2 = 0; s2 < 16; ++s2) {
      const float hend = hcS[ch][s2][ln];   // read hend BEFORE overwriting the slot
      hcS[ch][s2][ln] = carry;              // entering carry for chunk s2
      carry = EXP2F(AnE * sumDS[ch][s2]) * carry + hend;
    }
  }
  __syncthreads();
  // ---- truncated carry correction, dual-chain, tiled like pass 1 ----
  const float carryA = hcS[0][s][n], carryB = hcS[1][s][n];
  const float mcA = hmax32(fabsf(carryA));
  const float mcB = hmax32(fabsf(carryB));
  const float AmaxE0 = hmax32(AnE0);             // all < 0; max = slowest decay
  const float AmaxE1 = hmax32(AnE1);
  // smallest P with 32*mc*cmax*2^(AmaxE*P) <= 1e-4  (log2f(0) = -inf => skip)
  const float Pstop0 = log2f(mcA * cmaxS[s] * 3.2e5f) / (-AmaxE0);
  const float Pstop1 = log2f(mcB * cmaxS[s] * 3.2e5f) / (-AmaxE1);
  {
    float hA = carryA, hB = carryB, P0 = 0.f, P1 = 0.f;
    const float* cl = cP + (size_t)lbeg * Nn;
    for (int t8 = 0; t8 < LCc / 8; ++t8) {
      if (!(P0 < Pstop0) && !(P1 < Pstop1)) break;   // uniform per half-wave
      const int pb = pixbase(lbeg + t8 * 8, k);
      #pragma unroll
      for (int half = 0; half < 2; ++half) {
        const int gb = pb + half * 4 * pstr;
        const float2 u0 = ddS[0][gb], u1 = ddS[0][gb + pstr],
                     u2 = ddS[0][gb + 2 * pstr], u3 = ddS[0][gb + 3 * pstr];
        const float2 v0 = ddS[1][gb], v1 = ddS[1][gb + pstr],
                     v2 = ddS[1][gb + 2 * pstr], v3 = ddS[1][gb + 3 * pstr];
        hA *= EXP2F(u0.x * AnE0); pSA[s][half * 4 + 0][n] = hA * cl[0];
        hB *= EXP2F(v0.x * AnE1); pSB[s][half * 4 + 0][n] = hB * cl[0];
        hA *= EXP2F(u1.x * AnE0); pSA[s][half * 4 + 1][n] = hA * cl[Nn];
        hB *= EXP2F(v1.x * AnE1); pSB[s][half * 4 + 1][n] = hB * cl[Nn];
        hA *= EXP2F(u2.x * AnE0); pSA[s][half * 4 + 2][n] = hA * cl[2 * Nn];
        hB *= EXP2F(v2.x * AnE1); pSB[s][half * 4 + 2][n] = hB * cl[2 * Nn];
        hA *= EXP2F(u3.x * AnE0); pSA[s][half * 4 + 3][n] = hA * cl[3 * Nn];
        hB *= EXP2F(v3.x * AnE1); pSB[s][half * 4 + 3][n] = hB * cl[3 * Nn];
        P0 += (u0.x + u1.x) + (u2.x + u3.x);
        P1 += (v0.x + v1.x) + (v2.x + v3.x);
        cl += 4 * Nn;
      }
      const float4 a4 = *(const float4*)&pSA[s][rrow][qtr * 8];
      const float4 d4v = *(const float4*)&pSA[s][rrow][qtr * 8 + 4];
      float sumA = ((a4.x + a4.y) + (a4.z + a4.w)) + ((d4v.x + d4v.y) + (d4v.z + d4v.w));
      const float4 e4 = *(const float4*)&pSB[s][rrow][qtr * 8];
      const float4 f4 = *(const float4*)&pSB[s][rrow][qtr * 8 + 4];
      float sumB = ((e4.x + e4.y) + (e4.z + e4.w)) + ((f4.x + f4.y) + (f4.z + f4.w));
      sumA += __shfl_xor(sumA, 8);
      sumB += __shfl_xor(sumB, 8);
      sumA += __shfl_xor(sumA, 16);
      sumB += __shfl_xor(sumB, 16);
      if (n < 8) {
        yD0[pb + n * pstr] += sumA;   // below-threshold adds are harmless (more exact)
        yD1[pb + n * pstr] += sumB;
      }
    }
  }
}

// ---------------- K5: merge + Ds-term + out-LN + SiLU(z)* + out_proj + residual ----------------
// r13 version: 4 direction planes summed in registers during staging (ysS single
// plane, 8.4KB); block LDS ~29KB -> 5 blocks/CU.
__global__ __launch_bounds__(256) void k5_merge(
    const float* __restrict__ ys, const float* __restrict__ zb,
    const float* __restrict__ og, const float* __restrict__ ob,
    const float* __restrict__ Wo, const float* __restrict__ resid,
    const float* __restrict__ xc, const float* __restrict__ DsP,
    float* __restrict__ out)
{
  __shared__ float ysS[16][132];   // 132: break the d-stride bank alias
  __shared__ float xcS[16][128];
  __shared__ float tS[16][128];
  __shared__ float oS[64][17];
  const int tid = threadIdx.x;
  const int wv = tid >> 6, lane = tid & 63;
  const int pbase = blockIdx.x * 16;   // 16 consecutive l (16 | 48: no row straddle)
  const int b = pbase / Ll;
  const int lbase = pbase % Ll;
  {  // ys staging with 4-dir register sum: thread -> (d = tid>>2 (+64), float4 at l)
    const int li0 = (tid & 3) * 4, dh = tid >> 2;
    #pragma unroll
    for (int it = 0; it < 2; ++it) {
      const int d = dh + 64 * it;
      float4 acc = make_float4(0.f, 0.f, 0.f, 0.f);
      #pragma unroll
      for (int k = 0; k < 4; ++k) {
        const float4 v = *(const float4*)&ys[((size_t)(b * Kk + k) * Dd + d) * Ll + lbase + li0];
        acc.x += v.x; acc.y += v.y; acc.z += v.z; acc.w += v.w;
      }
      ysS[li0 + 0][d] = acc.x; ysS[li0 + 1][d] = acc.y;
      ysS[li0 + 2][d] = acc.z; ysS[li0 + 3][d] = acc.w;
    }
  }
  {  // xc (pixel-major): lanes along d, fully coalesced
    const int p = tid >> 4, q = tid & 15;
    const float4* src = (const float4*)&xc[((size_t)(b * Ll) + lbase + p) * Dd];
    ((float4*)xcS[p])[q]      = src[q];
    ((float4*)xcS[p])[q + 16] = src[q + 16];
  }
  float sDs[2];
  #pragma unroll
  for (int m = 0; m < 2; ++m) {
    const int dch = lane + 64 * m;
    sDs[m] = DsP[dch] + DsP[Dd + dch] + DsP[2 * Dd + dch] + DsP[3 * Dd + dch];
  }
  __syncthreads();
  for (int pi = 0; pi < 4; ++pi) {
    const int p = wv * 4 + pi;
    const int l0 = lbase + p;
    float tv[2];
    #pragma unroll
    for (int m = 0; m < 2; ++m) {
      const int dch = lane + 64 * m;
      tv[m] = ysS[p][dch] + sDs[m] * xcS[p][dch];
    }
    const float mu = wsum64(tv[0] + tv[1]) * (1.0f / 128.0f);
    const float q = wsum64((tv[0] - mu) * (tv[0] - mu) +
                           (tv[1] - mu) * (tv[1] - mu)) * (1.0f / 128.0f);
    const float rs = rsqrtf(q + EPSf);
    #pragma unroll
    for (int m = 0; m < 2; ++m) {
      const int dch = lane + 64 * m;
      const float zz = zb[(size_t)(b * Ll + l0) * Dd + dch];
      const float sig = 1.0f / (1.0f + __expf(-zz));
      tS[p][dch] = ((tv[m] - mu) * rs * og[dch] + ob[dch]) * (zz * sig);
    }
  }
  __syncthreads();
  float acc[4] = {0.f, 0.f, 0.f, 0.f};
  const float4* W4 = (const float4*)Wo;     // out_proj_w (64,128)
  for (int d4 = 0; d4 < 32; ++d4) {
    const float4 w4 = W4[lane * 32 + d4];
    #pragma unroll
    for (int pi = 0; pi < 4; ++pi) {
      const float4 t4 = ((const float4*)tS[wv * 4 + pi])[d4];
      acc[pi] += t4.x * w4.x + t4.y * w4.y + t4.z * w4.z + t4.w * w4.w;
    }
  }
  #pragma unroll
  for (int pi = 0; pi < 4; ++pi) oS[lane][wv * 4 + pi] = acc[pi];
  __syncthreads();
  const int c = tid >> 2, off = (tid & 3) * 4;
  const size_t obase = (size_t)(b * Cc + c) * Ll + lbase + off;
  const float4 r4 = *(const float4*)(resid + obase);
  float4 o4;
  o4.x = oS[c][off + 0] + r4.x;
  o4.y = oS[c][off + 1] + r4.y;
  o4.z = oS[c][off + 2] + r4.z;
  o4.w = oS[c][off + 3] + r4.w;
  *(float4*)(out + obase) = o4;
}

extern "C" void kernel_launch(void* const* d_in, const int* in_sizes, int n_in,
                              void* d_out, int out_size, void* d_ws, size_t ws_size,
                              hipStream_t stream)
{
  (void)in_sizes; (void)n_in; (void)out_size; (void)ws_size;
  const float* fufea1     = (const float*)d_in[0];
  const float* ln_g       = (const float*)d_in[1];
  const float* ln_b       = (const float*)d_in[2];
  const float* in_proj_w  = (const float*)d_in[3];
  const float* conv_w     = (const float*)d_in[4];
  const float* conv_b     = (const float*)d_in[5];
  const float* x_proj_w   = (const float*)d_in[6];
  const float* dt_w       = (const float*)d_in[7];
  const float* dt_b       = (const float*)d_in[8];
  const float* A_logs     = (const float*)d_in[9];
  const float* Ds         = (const float*)d_in[10];
  const float* out_ln_g   = (const float*)d_in[11];
  const float* out_ln_b   = (const float*)d_in[12];
  const float* out_proj_w = (const float*)d_in[13];

  float* ws = (float*)d_ws;
  // k4's 1-deep B/C prefetch overreads a few hundred bytes past Bm/Cm row ends
  // -> keep a live buffer after each (Bm -> Cm -> zb). dd2 is read via an exact
  // in-bounds LDS copy (no overread).
  float2* dd2 = (float2*)ws;        // (B,K,D,L) float2, PIXEL-major l  4718592 floats
  float* Bm   = ws + 4718592;       // (B,K,L,N) scan-major             589824
  float* Cm   = ws + 5308416;       // (B,K,L,N) scan-major             589824
  float* zb   = ws + 5898240;       // (B,L,D)                          589824
  float* xc   = ws + 6488064;       // (B,L,D) pixel-major              589824
  float* ysb  = ws + 7077888;       // (B,K,D,L) PIXEL-space l         2359296
  float* xin  = ws + 7077888;       // (B,L,D) pixel-major — overlaps ysb (dead before k4)
  // total: 9437184 floats = 37.75 MB

  k1_ln_inproj<<<288, 256, 0, stream>>>(fufea1, ln_g, ln_b, in_proj_w, xin, zb);
  k3_proj<<<576, 512, 0, stream>>>(xin, conv_w, conv_b, x_proj_w, dt_w, dt_b,
                                   xc, dd2, Bm, Cm);
  k4_scan<<<512, 512, 0, stream>>>(dd2, Bm, Cm, A_logs, ysb);
  k5_merge<<<288, 256, 0, stream>>>(ysb, zb, out_ln_g, out_ln_b, out_proj_w, fufea1,
                                    xc, Ds, (float*)d_out);
}